// Round 8
// baseline (215.629 us; speedup 1.0000x reference)
//
#include <hip/hip_runtime.h>

#define T    512
#define B    512
#define NT   64
#define NSEG 16
#define SEGL 32     // segments: s in [0,16); t-range [1+32s, min(33+32s,512)); seg 15 has 31 steps

typedef short bf16x8 __attribute__((ext_vector_type(8)));  // 8 bf16 (4 VGPRs)
typedef float f32x4  __attribute__((ext_vector_type(4)));

__device__ __forceinline__ float rflf(float x) {
    return __uint_as_float(__builtin_amdgcn_readfirstlane(__float_as_uint(x)));
}
__device__ __forceinline__ unsigned rne_bf16(float f) {
    unsigned u = __float_as_uint(f);
    u += 0x7fffu + ((u >> 16) & 1u);
    return u >> 16;
}
__device__ __forceinline__ float wsum(float v) {       // all-lanes wave sum
#pragma unroll
    for (int off = 32; off > 0; off >>= 1) v += __shfl_xor(v, off);
    return v;
}

// ---------------------------------------------------------------------------
// Segmented rank-1 scan for the CRF normalizer.
// q_t^T = q_{t-1}^T (E diag(X_t)) is LINEAR; positive-matrix segment products
// are rank-1 to ~tau^(L-1) (tau<=0.462, L=32 -> 4e-11): P_s ~= u_s r_s^T / c_s
// with u_s = P_s*1 (backward matvec chain), r_s^T = 1^T P_s (forward chain),
// c_s = sum(u_s). 2*B*NSEG = 16384 independent chains of <=32 steps replace
// the 511-step serial chain -> throughput-bound instead of latency-bound.
// Per step: R7-proven row-replicated-A MFMA matvec; A-build via
// 1x ds_write_b32 + 2x broadcast ds_read_b128 (was 8 bpermutes).
// Renorm: power-of-2 from lane-0 exponent every 4 steps; u-exponents cancel
// against c_s exactly, only forward-chain exponents Kr are kept.
// ---------------------------------------------------------------------------
__global__ __launch_bounds__(64) void crf_chains(
    const float* __restrict__ emissions,  // [T, B, NT]
    const int*   __restrict__ tags,       // [T, B]
    const int*   __restrict__ mask,       // [T, B]
    const float* __restrict__ startT,
    const float* __restrict__ endT,
    const float* __restrict__ trans,      // [NT, NT]
    float* __restrict__ out,
    float* __restrict__ Rws,              // [B][NSEG][NT]
    float* __restrict__ Uws,              // [B][NSEG][NT]
    int*   __restrict__ Kws)              // [B][NSEG]
{
    const int j  = threadIdx.x;
    const int id = blockIdx.x;

    __shared__ __align__(16) int pkbuf[32];   // packed bf16 pairs of the state

    if (id < 2 * B * NSEG) {
        const bool fwd = id < B * NSEG;
        const int  id2 = fwd ? id : id - B * NSEG;
        const int  b   = id2 >> 4;
        const int  s   = id2 & (NSEG - 1);
        const int  ts  = 1 + SEGL * s;
        const int  te  = (s == NSEG - 1) ? T : ts + SEGL;
        const int  len = te - ts;

        const int n = j & 15, quad = j >> 4;

        // B-frags: fwd -> B[k][n'] = E[k][n'];  bwd -> B[k][n'] = E[n'][k]
        bf16x8 Bf[4][2];
#pragma unroll
        for (int nt = 0; nt < 4; ++nt)
#pragma unroll
            for (int h = 0; h < 2; ++h) {
                int dw[4];
#pragma unroll
                for (int e2 = 0; e2 < 4; ++e2) {
                    const int k0 = h * 32 + quad * 8 + 2 * e2;
                    float v0, v1;
                    if (fwd) {
                        v0 = __expf(trans[k0 * NT + nt * 16 + n]);
                        v1 = __expf(trans[(k0 + 1) * NT + nt * 16 + n]);
                    } else {
                        v0 = __expf(trans[(nt * 16 + n) * NT + k0]);
                        v1 = __expf(trans[(nt * 16 + n) * NT + k0 + 1]);
                    }
                    dw[e2] = (int)(rne_bf16(v0) | (rne_bf16(v1) << 16));
                }
                int4 t4 = {dw[0], dw[1], dw[2], dw[3]};
                Bf[nt][h] = __builtin_bit_cast(bf16x8, t4);
            }

        // per-segment mask bits (lane tt -> step ts+tt)
        const int mv = (j < len) ? mask[(ts + j) * B + b] : 0;
        const unsigned long long mbc = __ballot(mv != 0);

        const float* pe = emissions + (size_t)b * NT + j;

        float st = 1.0f;     // state: r (fwd) or u (bwd)
        int   Kr = 0;

        // emission value pipeline (depth 2)
        int t0 = fwd ? ts : te - 1;
        int t1 = fwd ? ts + 1 : te - 2;
        if (t1 < ts) t1 = ts;
        if (t1 >= te) t1 = te - 1;
        float ecur = pe[(size_t)t0 * B * NT];
        float en1  = pe[(size_t)t1 * B * NT];

        for (int tt = 0; tt < len; ++tt) {
            // prefetch e two steps ahead
            int tn = fwd ? (ts + tt + 2) : (te - 1 - tt - 2);
            tn = (tn < ts) ? ts : ((tn >= te) ? te - 1 : tn);
            const float e2v = pe[(size_t)tn * B * NT];

            const float X = __expf(ecur);
            const float y = fwd ? st : st * X;   // bwd: u' = E (X o u)

            // pack y -> bf16 pairs; even lane 2i holds (y_2i, y_2i+1)
            const int qi    = __float_as_int(y);
            const int qswap = __builtin_amdgcn_update_dpp(0, qi, 0xB1, 0xF, 0xF, true);
            const int pk    = __builtin_amdgcn_perm((unsigned)qswap, (unsigned)qi,
                                                    0x07060302u);
            if (!(j & 1)) pkbuf[j >> 1] = pk;          // ds_write_b32, 32 banks
            const bf16x8 a0 = *(const bf16x8*)&pkbuf[quad * 4];        // k 8q..8q+7
            const bf16x8 a1 = *(const bf16x8*)&pkbuf[16 + quad * 4];   // +32

            const f32x4 z = {0.f, 0.f, 0.f, 0.f};
            f32x4 c0 = __builtin_amdgcn_mfma_f32_16x16x32_bf16(a0, Bf[0][0], z, 0, 0, 0);
            f32x4 c1 = __builtin_amdgcn_mfma_f32_16x16x32_bf16(a0, Bf[1][0], z, 0, 0, 0);
            f32x4 c2 = __builtin_amdgcn_mfma_f32_16x16x32_bf16(a0, Bf[2][0], z, 0, 0, 0);
            f32x4 c3 = __builtin_amdgcn_mfma_f32_16x16x32_bf16(a0, Bf[3][0], z, 0, 0, 0);
            c0 = __builtin_amdgcn_mfma_f32_16x16x32_bf16(a1, Bf[0][1], c0, 0, 0, 0);
            c1 = __builtin_amdgcn_mfma_f32_16x16x32_bf16(a1, Bf[1][1], c1, 0, 0, 0);
            c2 = __builtin_amdgcn_mfma_f32_16x16x32_bf16(a1, Bf[2][1], c2, 0, 0, 0);
            c3 = __builtin_amdgcn_mfma_f32_16x16x32_bf16(a1, Bf[3][1], c3, 0, 0, 0);

            float p = c0[0];
            p = (quad == 1) ? c1[0] : p;
            p = (quad == 2) ? c2[0] : p;
            p = (quad == 3) ? c3[0] : p;

            const int  bitidx = fwd ? tt : (len - 1 - tt);
            const bool mc     = (mbc >> bitidx) & 1ull;
            const float sn    = fwd ? p * X : p;
            st = mc ? sn : st;

            if ((tt & 3) == 3) {   // power-of-2 renorm
                const int bits = __builtin_amdgcn_readfirstlane(__float_as_int(st));
                const int k    = ((bits >> 23) & 255) - 127;
                st *= __int_as_float((127 - k) << 23);
                Kr += k;
            }
            ecur = en1; en1 = e2v;
        }

        if (fwd) {
            Rws[(size_t)(b * NSEG + s) * NT + j] = st;
            if (j == 0) Kws[b * NSEG + s] = Kr;
        } else {
            Uws[(size_t)(b * NSEG + s) * NT + j] = st;
        }

    } else {
        // ===================== numerator wave (R7-proven) ===================
        const int b = id - 2 * B * NSEG;
        float acc = 0.f;
        int   cnt = 0;
#pragma unroll
        for (int m = 0; m < T / 64; ++m) {
            const int t  = j + 64 * m;
            const int mv = mask[t * B + b];
            const int tg = tags[t * B + b];
            cnt += (int)__popcll(__ballot(mv != 0));
            if (t == 0) {
                acc += startT[tg] + emissions[(size_t)b * NT + tg];
            } else if (mv) {
                const int tp = tags[(t - 1) * B + b];
                acc += trans[tp * NT + tg]
                     + emissions[(size_t)(t * B + b) * NT + tg];
            }
        }
        acc = wsum(acc);
        if (j == 0) {
            const int last = tags[(size_t)(cnt - 1) * B + b];
            atomicAdd(out, acc + endT[last]);
        }
    }
}

// ---------------------------------------------------------------------------
// Combine: den_b = S0 + ln2*sum(Kr) + log(q0.U0) + sum_s log(R_s.U_{s+1})
//                + log(R_15.w) - sum_s log(sum U_s)
// ---------------------------------------------------------------------------
__global__ __launch_bounds__(64) void crf_combine(
    const float* __restrict__ emissions,
    const float* __restrict__ startT,
    const float* __restrict__ endT,
    const float* __restrict__ Rws,
    const float* __restrict__ Uws,
    const int*   __restrict__ Kws,
    float* __restrict__ out)
{
    const int b = blockIdx.x;
    const int j = threadIdx.x;

    const float em0 = emissions[(size_t)b * NT + j];
    const float sc0 = startT[j] + em0;
    const float S0  = rflf(sc0);
    const float q0  = __expf(sc0 - S0);
    const float w   = __expf(endT[j]);

    float Rv[NSEG], Uv[NSEG];
#pragma unroll
    for (int s = 0; s < NSEG; ++s) {
        Rv[s] = Rws[(size_t)(b * NSEG + s) * NT + j];
        Uv[s] = Uws[(size_t)(b * NSEG + s) * NT + j];
    }
    int kv = (j < NSEG) ? Kws[b * NSEG + j] : 0;
#pragma unroll
    for (int off = 32; off > 0; off >>= 1) kv += __shfl_xor(kv, off);

    float acc = S0 + 0.69314718f * (float)kv;
    acc += __logf(wsum(q0 * Uv[0]));
#pragma unroll
    for (int s = 0; s < NSEG - 1; ++s)
        acc += __logf(wsum(Rv[s] * Uv[s + 1]));
    acc += __logf(wsum(Rv[NSEG - 1] * w));
#pragma unroll
    for (int s = 0; s < NSEG; ++s)
        acc -= __logf(wsum(Uv[s]));

    if (j == 0)
        atomicAdd(out, -acc);   // llh = num - den
}

extern "C" void kernel_launch(void* const* d_in, const int* in_sizes, int n_in,
                              void* d_out, int out_size, void* d_ws, size_t ws_size,
                              hipStream_t stream) {
    const float* emissions = (const float*)d_in[0];
    const int*   tags      = (const int*)  d_in[1];
    const int*   mask      = (const int*)  d_in[2];
    const float* startT    = (const float*)d_in[3];
    const float* endT      = (const float*)d_in[4];
    const float* trans     = (const float*)d_in[5];
    float* out = (float*)d_out;

    float* Rws = (float*)d_ws;                       // 2 MB
    float* Uws = Rws + (size_t)B * NSEG * NT;        // 2 MB
    int*   Kws = (int*)(Uws + (size_t)B * NSEG * NT); // 32 KB

    hipMemsetAsync(out, 0, sizeof(float), stream);
    crf_chains<<<2 * B * NSEG + B, 64, 0, stream>>>(
        emissions, tags, mask, startT, endT, trans, out, Rws, Uws, Kws);
    crf_combine<<<B, 64, 0, stream>>>(
        emissions, startT, endT, Rws, Uws, Kws, out);
}